// Round 2
// baseline (441.193 us; speedup 1.0000x reference)
//
#include <hip/hip_runtime.h>

// Inverse 2D Haar DWT (pywt idwt2, 'haar').
// Input:  ll/lh/hl/hh, each (B,C,H,W) = (4,64,256,256) fp32.
// Output: (B,C,2H,2W) fp32.
// Per input coeff (h,w):
//   out[2h,  2w]   = (ll+lh+hl+hh)*0.5   (a)
//   out[2h,  2w+1] = (ll+lh-hl-hh)*0.5   (b)
//   out[2h+1,2w]   = (ll-lh+hl-hh)*0.5   (c)
//   out[2h+1,2w+1] = (ll-lh-hl+hh)*0.5   (d)
//
// vs the 428.9 µs version:
//  - float4-width loads (16 B/lane) instead of float2
//  - grid-stride loop, grid capped at 2048 blocks (256 CU x 8)
//  - nontemporal loads+stores (pure streaming data)
//  - NOTE: nontemporal builtins require clang ext_vector_type, not
//    HIP_vector_type (float4) — hence the v4f typedef.

typedef float v4f __attribute__((ext_vector_type(4)));

#define W4        64    // v4f slots per input row  (256/4)
#define OUT_SLOTS 128   // v4f slots per output row (512/4)
#define H_IN      256

__global__ __launch_bounds__(256) void idwt2_haar_kernel(
    const v4f* __restrict__ ll4, const v4f* __restrict__ lh4,
    const v4f* __restrict__ hl4, const v4f* __restrict__ hh4,
    v4f* __restrict__ out4, int n_chunks) {
    const int stride = gridDim.x * blockDim.x;
    for (int idx = blockIdx.x * blockDim.x + threadIdx.x; idx < n_chunks;
         idx += stride) {
        int j       = idx & (W4 - 1);      // v4f slot within input row
        int rowflat = idx >> 6;            // flat input row in [0, B*C*H)
        int r       = rowflat & (H_IN - 1);
        int img     = rowflat >> 8;        // image index in [0, B*C)

        const v4f vll = __builtin_nontemporal_load(ll4 + idx);
        const v4f vlh = __builtin_nontemporal_load(lh4 + idx);
        const v4f vhl = __builtin_nontemporal_load(hl4 + idx);
        const v4f vhh = __builtin_nontemporal_load(hh4 + idx);

        v4f e0, e1, o0, o1;  // even-row slots 2j,2j+1; odd-row slots
        {   // input col 4j   -> output cols 8j, 8j+1
            float s01 = vll.x + vlh.x, d01 = vll.x - vlh.x;
            float s23 = vhl.x + vhh.x, d23 = vhl.x - vhh.x;
            e0.x = 0.5f * (s01 + s23);   // a
            e0.y = 0.5f * (s01 - s23);   // b
            o0.x = 0.5f * (d01 + d23);   // c
            o0.y = 0.5f * (d01 - d23);   // d
        }
        {   // input col 4j+1 -> output cols 8j+2, 8j+3
            float s01 = vll.y + vlh.y, d01 = vll.y - vlh.y;
            float s23 = vhl.y + vhh.y, d23 = vhl.y - vhh.y;
            e0.z = 0.5f * (s01 + s23);
            e0.w = 0.5f * (s01 - s23);
            o0.z = 0.5f * (d01 + d23);
            o0.w = 0.5f * (d01 - d23);
        }
        {   // input col 4j+2 -> output cols 8j+4, 8j+5
            float s01 = vll.z + vlh.z, d01 = vll.z - vlh.z;
            float s23 = vhl.z + vhh.z, d23 = vhl.z - vhh.z;
            e1.x = 0.5f * (s01 + s23);
            e1.y = 0.5f * (s01 - s23);
            o1.x = 0.5f * (d01 + d23);
            o1.y = 0.5f * (d01 - d23);
        }
        {   // input col 4j+3 -> output cols 8j+6, 8j+7
            float s01 = vll.w + vlh.w, d01 = vll.w - vlh.w;
            float s23 = vhl.w + vhh.w, d23 = vhl.w - vhh.w;
            e1.z = 0.5f * (s01 + s23);
            e1.w = 0.5f * (s01 - s23);
            o1.z = 0.5f * (d01 + d23);
            o1.w = 0.5f * (d01 - d23);
        }

        // Output v4f base: even row = img*512 + 2r, odd row = +1 row.
        int base0 = ((img << 9) + (r << 1)) * OUT_SLOTS + (j << 1);
        __builtin_nontemporal_store(e0, out4 + base0);
        __builtin_nontemporal_store(e1, out4 + base0 + 1);
        __builtin_nontemporal_store(o0, out4 + base0 + OUT_SLOTS);
        __builtin_nontemporal_store(o1, out4 + base0 + OUT_SLOTS + 1);
    }
}

extern "C" void kernel_launch(void* const* d_in, const int* in_sizes, int n_in,
                              void* d_out, int out_size, void* d_ws, size_t ws_size,
                              hipStream_t stream) {
    const v4f* ll = (const v4f*)d_in[0];
    const v4f* lh = (const v4f*)d_in[1];
    const v4f* hl = (const v4f*)d_in[2];
    const v4f* hh = (const v4f*)d_in[3];
    v4f* out = (v4f*)d_out;

    int n        = in_sizes[0];   // 16,777,216 elements per input
    int n_chunks = n >> 2;        // one chunk per input v4f = 4,194,304
    int block    = 256;
    int grid     = (n_chunks + block - 1) / block;
    if (grid > 2048) grid = 2048; // 256 CU x 8 blocks; grid-stride the rest

    idwt2_haar_kernel<<<grid, block, 0, stream>>>(ll, lh, hl, hh, out, n_chunks);
}

// Round 4
// 424.324 us; speedup vs baseline: 1.0398x; 1.0398x over previous
//
#include <hip/hip_runtime.h>

// Inverse 2D Haar DWT (pywt idwt2, 'haar').
// Input:  ll/lh/hl/hh, each (B,C,H,W) = (4,64,256,256) fp32.
// Output: (B,C,2H,2W) fp32.
// Per input coeff (h,w):
//   out[2h,  2w]   = (ll+lh+hl+hh)*0.5   (a)
//   out[2h,  2w+1] = (ll+lh-hl-hh)*0.5   (b)
//   out[2h+1,2w]   = (ll-lh+hl-hh)*0.5   (c)
//   out[2h+1,2w+1] = (ll-lh-hl+hh)*0.5   (d)
//
// Mapping (the dense-store one): one thread = one output float4 slot s of a
// row-pair. Needs input cols 2s,2s+1 = one float2 per input (8 B/lane,
// fully coalesced, 512 B per wave-instruction). Stores: consecutive lanes ->
// consecutive float4 slots: fully dense 1 KiB wave stores to rows 2r, 2r+1.
// (Round-2 float4-load variant had lanes storing at stride-2 slots ->
//  half-filled 64 B segments -> 2x store transactions. Reverted.)
// Kept from round 2: nontemporal loads/stores (pure streaming, no reuse),
// grid-stride loop capped at 2048 blocks (256 CU x 8 waves).
// (Round 3 was an infra failure; this source is unchanged from Round 2's
//  proposal to preserve the A/B against the 441 µs strided-store variant.)

typedef float v2f __attribute__((ext_vector_type(2)));
typedef float v4f __attribute__((ext_vector_type(4)));

#define SLOTS 128   // float4 slots per output row (512/4)
#define H_IN  256

__global__ __launch_bounds__(256) void idwt2_haar_kernel(
    const v2f* __restrict__ ll2, const v2f* __restrict__ lh2,
    const v2f* __restrict__ hl2, const v2f* __restrict__ hh2,
    v4f* __restrict__ out4, int n_threads) {
    const int stride = gridDim.x * blockDim.x;
#pragma unroll 2
    for (int idx = blockIdx.x * blockDim.x + threadIdx.x; idx < n_threads;
         idx += stride) {
        int s       = idx & (SLOTS - 1);     // output float4 slot within row
        int rowflat = idx >> 7;              // flat input row in [0, B*C*H)
        int r       = rowflat & (H_IN - 1);  // row within image
        int img     = rowflat >> 8;          // image in [0, B*C)

        // float2 index == idx: input cols 2s, 2s+1 of this input row
        const v2f vll = __builtin_nontemporal_load(ll2 + idx);
        const v2f vlh = __builtin_nontemporal_load(lh2 + idx);
        const v2f vhl = __builtin_nontemporal_load(hl2 + idx);
        const v2f vhh = __builtin_nontemporal_load(hh2 + idx);

        v4f r0, r1;
        {   // input col 2s -> output cols 4s, 4s+1
            float s01 = vll.x + vlh.x, d01 = vll.x - vlh.x;
            float s23 = vhl.x + vhh.x, d23 = vhl.x - vhh.x;
            r0.x = 0.5f * (s01 + s23);   // a
            r0.y = 0.5f * (s01 - s23);   // b
            r1.x = 0.5f * (d01 + d23);   // c
            r1.y = 0.5f * (d01 - d23);   // d
        }
        {   // input col 2s+1 -> output cols 4s+2, 4s+3
            float s01 = vll.y + vlh.y, d01 = vll.y - vlh.y;
            float s23 = vhl.y + vhh.y, d23 = vhl.y - vhh.y;
            r0.z = 0.5f * (s01 + s23);
            r0.w = 0.5f * (s01 - s23);
            r1.z = 0.5f * (d01 + d23);
            r1.w = 0.5f * (d01 - d23);
        }

        // Output float4 base: flat output row = img*512 + 2r.
        int base0 = ((img << 9) + (r << 1)) * SLOTS + s;
        __builtin_nontemporal_store(r0, out4 + base0);          // row 2r
        __builtin_nontemporal_store(r1, out4 + base0 + SLOTS);  // row 2r+1
    }
}

extern "C" void kernel_launch(void* const* d_in, const int* in_sizes, int n_in,
                              void* d_out, int out_size, void* d_ws, size_t ws_size,
                              hipStream_t stream) {
    const v2f* ll = (const v2f*)d_in[0];
    const v2f* lh = (const v2f*)d_in[1];
    const v2f* hl = (const v2f*)d_in[2];
    const v2f* hh = (const v2f*)d_in[3];
    v4f* out = (v4f*)d_out;

    int n         = in_sizes[0];  // 16,777,216 elements per input
    int n_threads = n >> 1;       // one thread per input float2 = 8,388,608
    int block     = 256;
    int grid      = (n_threads + block - 1) / block;
    if (grid > 2048) grid = 2048; // 256 CU x 8 blocks; grid-stride the rest

    idwt2_haar_kernel<<<grid, block, 0, stream>>>(ll, lh, hl, hh, out, n_threads);
}